// Round 6
// baseline (4845.256 us; speedup 1.0000x reference)
//
#include <hip/hip_runtime.h>

// Decoder: 2-layer LSTM, B=1024, IN=256, H=512, OUT=256, T2=128 (hardcoded).
// PERSISTENT kernel, 256 blocks x 512 thr, 1 block/CU (~120KB LDS static).
// Round-9: K-flipped DMA pipeline. 16 batch-groups of 64 rows, 16 j-blocks,
// XCD-LOCAL (2 groups per XCD), barrier-free dataflow handshakes.
//   - K-order flipped: cell0 K=[h0 512 | z 256], cell1 K=[h1 512 | h0 512].
//     The leading 8 granules of each cell read PREVIOUS-step data that is
//     provably ready at phase entry (counter algebra: full(t-1)==half(t)),
//     so A(0..2) + B-warm(0..5) all issue BEFORE the handshake wait ->
//     the poll window streams 15 loads; no post-wait serial A-latency.
//   - B 6-deep, A 3-deep; exact in-order vmcnt tiers (warmup 2/4/6,
//     steady 8, taper 6/4/2/1/0) enumerated load-by-load.
//   - loop-invariant L2 loads hoisted to VGPRs (gate biases, fc/lin bias,
//     proj B-fragments) — buffer_inv kills L1 reuse every step otherwise.
//   - weights pre-swizzled to MFMA B-frag order (granule-contiguous 16KB);
//     c-state in VGPRs; activations through XCD-local L2 (plain st/ld +
//     buffer_inv at handshakes).

typedef __attribute__((ext_vector_type(8))) __bf16 bf16x8;
typedef __attribute__((ext_vector_type(16))) float f32x16;
typedef unsigned long long ull;

__device__ __forceinline__ f32x16 mfma_bf16(bf16x8 a, bf16x8 b, f32x16 c) {
  return __builtin_amdgcn_mfma_f32_32x32x16_bf16(a, b, c, 0, 0, 0);
}

__device__ __forceinline__ short f2bf(float f) {  // RNE fp32->bf16
  unsigned u = __float_as_uint(f);
  u += 0x7fffu + ((u >> 16) & 1u);
  return (short)(u >> 16);
}

__device__ __forceinline__ float sigm(float x) { return 1.0f / (1.0f + __expf(-x)); }
__device__ __forceinline__ float tanh_fast(float x) { return 2.0f / (1.0f + __expf(-2.0f * x)) - 1.0f; }

__device__ __forceinline__ f32x16 zero16() {
  f32x16 z;
#pragma unroll
  for (int i = 0; i < 16; ++i) z[i] = 0.0f;
  return z;
}

__device__ __forceinline__ void dma16(const void* g, void* l) {
  __builtin_amdgcn_global_load_lds(
      (const __attribute__((address_space(1))) void*)g,
      (__attribute__((address_space(3))) void*)l, 16, 0, 0);
}

// proj A-tile LDS layout: row m (0..63) at stride 132 shorts (padded).
#define AT_STRIDE 132

// ---------------------------------------------------------------------------
// prep: swizzle weights into MFMA B-frag order (granule-contiguous), with the
// FLIPPED K-order; sum biases; init bf16 states; init ready-counters
// (cnt[z1]=8, cnt[h0_0]=16, cnt[h1_0]=16 — prep is the t=-1 producer).
// flags: per group g: flags[g*256 + type*32], type 0=z[0],1=z[1],2=h0[0],
// 3=h0[1],4=h1[0],5=h1[1]. XCD ctrs at 8192+x*32.
// ---------------------------------------------------------------------------
__global__ __launch_bounds__(256) void prep_kernel(
    const float* __restrict__ z0, const float* __restrict__ h0in,
    const float* __restrict__ Wih0, const float* __restrict__ Whh0,
    const float* __restrict__ bih0, const float* __restrict__ bhh0,
    const float* __restrict__ Wih1, const float* __restrict__ Whh1,
    const float* __restrict__ bih1, const float* __restrict__ bhh1,
    const float* __restrict__ fcW, const float* __restrict__ linW,
    short* __restrict__ wsw0, short* __restrict__ wsw1,
    short* __restrict__ fcWsw, short* __restrict__ linWsw,
    float* __restrict__ bias0, float* __restrict__ bias1,
    short* __restrict__ zb1, short* __restrict__ h0b0, short* __restrict__ h1b0,
    int* __restrict__ flags)
{
  int idx = blockIdx.x * 256 + threadIdx.x;
  if (idx < 1572864) {  // wsw0 [j16][s48][g4][l64][8]; K=768 = [h0 512 | z 256]
    int jj = idx & 7, l = (idx >> 3) & 63, gg = (idx >> 9) & 3;
    int rest = idx >> 11;           // j*48 + s
    int s = rest % 48, b = rest / 48;
    int row = gg * 512 + b * 32 + (l & 31);
    int k = s * 16 + (l >> 5) * 8 + jj;
    wsw0[idx] = f2bf(k < 512 ? Whh0[row * 512 + k] : Wih0[row * 256 + (k - 512)]);
    return;
  }
  idx -= 1572864;
  if (idx < 2097152) {  // wsw1 [j16][s64][g4][l64][8]; K=1024 = [h1 512 | h0 512]
    int jj = idx & 7, l = (idx >> 3) & 63, gg = (idx >> 9) & 3;
    int rest = idx >> 11;           // j*64 + s
    int s = rest & 63, b = rest >> 6;
    int row = gg * 512 + b * 32 + (l & 31);
    int k = s * 16 + (l >> 5) * 8 + jj;
    wsw1[idx] = f2bf(k < 512 ? Whh1[row * 512 + k] : Wih1[row * 512 + (k - 512)]);
    return;
  }
  idx -= 2097152;
  if (idx < 131072) {  // fcWsw [jz8][s32][l64][8]
    int jj = idx & 7, l = (idx >> 3) & 63, s = (idx >> 9) & 31, jz = idx >> 14;
    int col = jz * 32 + (l & 31);
    int k = s * 16 + (l >> 5) * 8 + jj;
    fcWsw[idx] = f2bf(fcW[col * 512 + k]);
    return;
  }
  idx -= 131072;
  if (idx < 65536) {  // linWsw [jo8][s16][l64][8]
    int jj = idx & 7, l = (idx >> 3) & 63, s = (idx >> 9) & 15, jo = idx >> 13;
    int col = jo * 32 + (l & 31);
    int k = s * 16 + (l >> 5) * 8 + jj;
    linWsw[idx] = f2bf(linW[col * 256 + k]);
    return;
  }
  idx -= 65536;
  if (idx < 2048) { bias0[idx] = bih0[idx] + bhh0[idx]; return; }
  idx -= 2048;
  if (idx < 2048) { bias1[idx] = bih1[idx] + bhh1[idx]; return; }
  idx -= 2048;
  if (idx < 262144) { zb1[idx] = f2bf(z0[idx]); return; }
  idx -= 262144;
  if (idx < 524288) { h0b0[idx] = f2bf(h0in[idx]); return; }
  idx -= 524288;
  if (idx < 524288) { h1b0[idx] = f2bf(h0in[524288 + idx]); return; }
  idx -= 524288;
  if (idx < 8448) {  // ready-counters + xcd ctrs
    int v = 0;
    if (idx < 8192) {
      int off = idx & 255;
      if (off == 32) v = 8;                       // cnt_z[1] (prep wrote zb1)
      else if (off == 64 || off == 128) v = 16;   // cnt_h0[0], cnt_h1[0]
    }
    flags[idx] = v;
    return;
  }
}

// ---------------------------------------------------------------------------
// Dataflow sync: producers add 1 (after vmcnt drain); consumers poll to a
// monotone target, then buffer_inv (per-CU L1 invalidate; XCD L2 stays warm).
// ---------------------------------------------------------------------------
__device__ __forceinline__ void wait1(int* c0, int v0) {
  __syncthreads();
  if (threadIdx.x == 0) {
    while (__hip_atomic_load(c0, __ATOMIC_RELAXED, __HIP_MEMORY_SCOPE_AGENT) < v0)
      __builtin_amdgcn_s_sleep(2);
    asm volatile("buffer_inv" ::: "memory");
  }
  __syncthreads();
}

__device__ __forceinline__ void wait2(int* c0, int v0, int* c1, int v1) {
  __syncthreads();
  if (threadIdx.x == 0) {
    while (__hip_atomic_load(c0, __ATOMIC_RELAXED, __HIP_MEMORY_SCOPE_AGENT) < v0 ||
           __hip_atomic_load(c1, __ATOMIC_RELAXED, __HIP_MEMORY_SCOPE_AGENT) < v1)
      __builtin_amdgcn_s_sleep(2);
    asm volatile("buffer_inv" ::: "memory");
  }
  __syncthreads();
}

__device__ __forceinline__ void produce(int* c) {
  asm volatile("s_waitcnt vmcnt(0)" ::: "memory");
  __syncthreads();
  if (threadIdx.x == 0)
    __hip_atomic_fetch_add(c, 1, __ATOMIC_RELAXED, __HIP_MEMORY_SCOPE_AGENT);
}

// ---------------------------------------------------------------------------
// B warm: first 6 weight granules (96KB, immutable) — issued BEFORE the
// handshake wait. Leading __syncthreads closes previous gbuf/Atp readers of
// the aliased Bl region.
// ---------------------------------------------------------------------------
__device__ __forceinline__ void cell_warm(short* Bl, const short* __restrict__ wgl) {
  __syncthreads();
  const int t = threadIdx.x, w = t >> 6;
#pragma unroll
  for (int g = 0; g < 6; ++g)
#pragma unroll
    for (int i = 0; i < 2; ++i)
      dma16(wgl + (size_t)g * 8192 + (i * 512 + t) * 8,
            Bl + g * 8192 + i * 4096 + w * 512);
}

// A prologue: granules 0..2 (always from srcA under the flipped K-order).
// For P1 (h0(t-1)) and P2/j<8 (h1(t-1)) this is issued BEFORE the wait —
// readiness proven by the counter algebra (see header comment).
__device__ __forceinline__ void proA3(short* Al, const short* __restrict__ srcA,
                                      int ldA, int row0) {
  const int t = threadIdx.x, w = t >> 6, l = t & 63;
#pragma unroll
  for (int g = 0; g < 3; ++g)
    dma16(srcA + (size_t)(row0 + l) * ldA + g * 64 + w * 8,
          Al + g * 4096 + w * 512);
}

// ---------------------------------------------------------------------------
// DMA-pipelined LSTM cell phase (M=64, K granule = 64, 512 threads).
//   A LDS (K-major, 8KB/granule): slot (k8slice*64+row)*8 shorts, 3 buffers.
//   B LDS: granule 16KB = [u4][gate4][l64][8 shorts], 6 buffers (0..5 warmed).
//   Prologue (12 B + 3 A) issued by cell_warm/proA3 before entry.
//   Tiers (enumerated): g0:2 g1:4 g2:6; steady 8 (g+6<=NG); taper 6/4/2/1/0.
// ---------------------------------------------------------------------------
template <int NG, int TAG>
__device__ __forceinline__ void cell_phase_dma(
    short* Al, short* Bl, float* gbuf,
    const short* __restrict__ srcA, int ldA,
    const short* __restrict__ srcB, int ldB,
    const short* __restrict__ wgl,
    const float (&br)[4][4],
    float* cr, short* hout, int row0, int j0)
{
  const int t = threadIdx.x;           // 0..511, 8 waves
  const int w = t >> 6, l = t & 63;
  const int gq = w >> 1, mh = w & 1;   // wave = (gate quadrant, m-half)
  const int ln = l & 31, kh = l >> 5;

  auto issueA = [&](int g) {
    const short* asrc; int ald, gk;
    if (g < TAG) { asrc = srcA; ald = ldA; gk = g * 64; }
    else         { asrc = srcB; ald = ldB; gk = (g - TAG) * 64; }
    const short* gp = asrc + (size_t)(row0 + l) * ald + gk + w * 8;
    dma16(gp, Al + (g % 3) * 4096 + w * 512);
  };
  auto issueB = [&](int g) {
    const short* gb = wgl + (size_t)g * 8192;
    short* lb = Bl + (g % 6) * 8192;
#pragma unroll
    for (int i = 0; i < 2; ++i)
      dma16(gb + (i * 512 + t) * 8, lb + i * 4096 + w * 512);
  };

  f32x16 acc = zero16();

#pragma unroll
  for (int g = 0; g < NG; ++g) {
    // exact in-order vmcnt: A(g),B(g) complete when <= tier remain.
    if (g == 0)           asm volatile("s_waitcnt vmcnt(2)" ::: "memory");
    else if (g == 1)      asm volatile("s_waitcnt vmcnt(4)" ::: "memory");
    else if (g == 2)      asm volatile("s_waitcnt vmcnt(6)" ::: "memory");
    else if (g + 6 <= NG) asm volatile("s_waitcnt vmcnt(8)" ::: "memory");
    else if (g + 5 == NG) asm volatile("s_waitcnt vmcnt(6)" ::: "memory");
    else if (g + 4 == NG) asm volatile("s_waitcnt vmcnt(4)" ::: "memory");
    else if (g + 3 == NG) asm volatile("s_waitcnt vmcnt(2)" ::: "memory");
    else if (g + 2 == NG) asm volatile("s_waitcnt vmcnt(1)" ::: "memory");
    else                  asm volatile("s_waitcnt vmcnt(0)" ::: "memory");
    __builtin_amdgcn_s_barrier();          // granule g fully in LDS (all waves)
    __builtin_amdgcn_sched_barrier(0);
    const short* al = Al + (g % 3) * 4096;
    const short* bl = Bl + (g % 6) * 8192;
#pragma unroll
    for (int u = 0; u < 4; ++u) {
      bf16x8 a = *(const bf16x8*)&al[((u * 2 + kh) * 64 + mh * 32 + ln) * 8];
      bf16x8 b = *(const bf16x8*)&bl[((u * 4 + gq) * 64 + l) * 8];
      acc = mfma_bf16(a, b, acc);
    }
    __builtin_amdgcn_sched_barrier(0);
    __builtin_amdgcn_s_barrier();          // all waves done reading granule g
    __builtin_amdgcn_sched_barrier(0);
    if (g + 3 < NG) issueA(g + 3);         // refills A slot just read
    if (g + 6 < NG) issueB(g + 6);         // refills B slot just read
  }

  // C layout: col = lane&31, row = (r&3)+8*(r>>2)+4*(lane>>5) (+32 for mh=1).
  // gbuf aliases B buffers (pipeline drained: vmcnt(0) at g=NG-1 + barrier).
#pragma unroll
  for (int r = 0; r < 16; ++r) {
    int mloc = (r & 3) + 8 * (r >> 2) + 4 * kh + mh * 32;
    gbuf[(gq * 64 + mloc) * 32 + ln] = acc[r];
  }
  __syncthreads();
  const int m = t >> 3, nb = (t & 7) * 4;  // m 0..63, nb 0..28
  short hh[4];
#pragma unroll
  for (int u = 0; u < 4; ++u) {
    int n = nb + u;
    float gi = gbuf[(0 * 64 + m) * 32 + n] + br[0][u];
    float gf = gbuf[(1 * 64 + m) * 32 + n] + br[1][u];
    float gg = gbuf[(2 * 64 + m) * 32 + n] + br[2][u];
    float go = gbuf[(3 * 64 + m) * 32 + n] + br[3][u];
    float cn = sigm(gf) * cr[u] + sigm(gi) * tanh_fast(gg);
    cr[u] = cn;
    hh[u] = f2bf(sigm(go) * tanh_fast(cn));
  }
  ull hv; __builtin_memcpy(&hv, hh, 8);
  *(ull*)&hout[(size_t)(row0 + m) * 512 + j0 + nb] = hv;  // plain: same-XCD L2
}

// ---------------------------------------------------------------------------
// Projection partials (fc or lin), M=64, 512 thr: waves (kq = w>>1, mh = w&1).
// ALL A-stage loads AND B-fragments prefetched into VGPRs upfront (one
// latency each, outside the syncthreads fences). 4 K-partials -> gbuf.
// ---------------------------------------------------------------------------
template <int NQ>
__device__ __forceinline__ void proj_partials(
    short* At0, float* gbuf,
    const short* __restrict__ src, int ld,
    const short* __restrict__ wblk, int row0)
{
  const int t = threadIdx.x;
  const int w = t >> 6, l = t & 63;
  const int kq = w >> 1, mh = w & 1;
  const int ln = l & 31, kh = l >> 5;
  const int sks = t & 15, sm = t >> 4;   // staging: ks 0..15, m 0..31 (+32)
  f32x16 acc = zero16();
  uint4 pre[NQ][2];
  bf16x8 bfr[NQ][2];
#pragma unroll
  for (int q = 0; q < NQ; ++q) {
#pragma unroll
    for (int i = 0; i < 2; ++i)
      pre[q][i] = *(const uint4*)&src[(row0 + sm + 32 * i) * ld + q * 128 + sks * 8];
#pragma unroll
    for (int sl = 0; sl < 2; ++sl)
      bfr[q][sl] = *(const bf16x8*)&wblk[((q * 8 + kq * 2 + sl) * 64 + l) * 8];
  }
#pragma unroll
  for (int q = 0; q < NQ; ++q) {
    __syncthreads();
#pragma unroll
    for (int i = 0; i < 2; ++i)
      *(uint4*)&At0[(sm + 32 * i) * AT_STRIDE + sks * 8] = pre[q][i];
    __syncthreads();
#pragma unroll
    for (int sl = 0; sl < 2; ++sl) {
      int s16 = kq * 2 + sl;
      bf16x8 a = *(const bf16x8*)&At0[(mh * 32 + ln) * AT_STRIDE + (s16 * 2 + kh) * 8];
      acc = mfma_bf16(a, bfr[q][sl], acc);
    }
  }
  __syncthreads();
#pragma unroll
  for (int r = 0; r < 16; ++r) {
    int mloc = (r & 3) + 8 * (r >> 2) + 4 * kh + mh * 32;
    gbuf[(kq * 64 + mloc) * 32 + ln] = acc[r];
  }
  __syncthreads();
}

__global__ __launch_bounds__(512, 1) void decoder_persist(
    const short* __restrict__ wsw0, const short* __restrict__ wsw1,
    const short* __restrict__ fcWsw, const short* __restrict__ linWsw,
    const float* __restrict__ bias0, const float* __restrict__ bias1,
    const float* __restrict__ fcb, const float* __restrict__ linb,
    const float* __restrict__ c0in,
    short* h0x, short* h0y, short* h1x, short* h1y, short* zx, short* zy,
    int* flags, float* __restrict__ outp)
{
  __shared__ __align__(16) short Al[12288];   // 24 KB: A granules, 3 buffers
  __shared__ __align__(16) short Bl[49152];   // 96 KB: B granules, 6 buffers
  __shared__ int sgj[2];
  float* gbuf = (float*)Bl;                   // 32 KB cell gbuf, aliases B
  short* Atp = Bl;                            // proj A-stage (16896 B)
  float* gbufp = (float*)(Bl + 8448);         // proj gbuf (32 KB), after Atp

  // --- self-assignment: physical XCD id -> (group, j) slot ---
  if (threadIdx.x == 0) {
    unsigned xcc;
    asm volatile("s_getreg_b32 %0, hwreg(HW_REG_XCC_ID, 0, 32)" : "=s"(xcc));
    xcc &= 7u;
    int slot = __hip_atomic_fetch_add(&flags[8192 + (int)xcc * 32], 1,
                                      __ATOMIC_RELAXED, __HIP_MEMORY_SCOPE_AGENT);
    slot &= 31;                           // hardening: wrong-answer > hang
    sgj[0] = (int)xcc * 2 + (slot >> 4);  // group: 2 per XCD
    sgj[1] = slot & 15;                   // j-tile within group
  }
  __syncthreads();
  const int g = sgj[0], j = sgj[1];
  const int row0 = g * 64, j0 = j * 32;
  int* cnt = &flags[g * 256];             // 6 counters, one cacheline each
#define CZ(i)  (cnt + (0 + (i)) * 32)
#define CH0(i) (cnt + (2 + (i)) * 32)
#define CH1(i) (cnt + (4 + (i)) * 32)

  // --- c-state + loop-invariant biases in registers for the whole run ---
  float c0r[4], c1r[4], b0r[4][4], b1r[4][4], fbr[4];
  {
    const int m = threadIdx.x >> 3, nb = (threadIdx.x & 7) * 4;
#pragma unroll
    for (int u = 0; u < 4; ++u) {
      c0r[u] = c0in[(size_t)(row0 + m) * 512 + j0 + nb + u];
      c1r[u] = c0in[524288 + (size_t)(row0 + m) * 512 + j0 + nb + u];
      int jn = j0 + nb + u;
#pragma unroll
      for (int gt = 0; gt < 4; ++gt) {
        b0r[gt][u] = bias0[gt * 512 + jn];
        b1r[gt][u] = bias1[gt * 512 + jn];
      }
      fbr[u] = (j < 8) ? fcb[j * 32 + nb + u] : linb[(j - 8) * 32 + nb + u];
    }
  }

  short* h0buf[2] = {h0x, h0y};
  short* h1buf[2] = {h1x, h1y};
  short* zbuf[2] = {zx, zy};
  const short* wg0 = wsw0 + j * 98304;
  const short* wg1 = wsw1 + j * 131072;
  const short* wpj = (j < 8) ? (fcWsw + j * 16384) : (linWsw + (j - 8) * 8192);

#pragma unroll 1
  for (int t = 0; t < 128; ++t) {
    const int p = t & 1;
    const int half = (t >> 1) + 1;        // completed write-rounds, t-1 parity
    const int full = (t + 3) >> 1;        // incl. this step
    // P1: cell0  (K = [h0(t-1) 512 | z(t-1) 256]); B-warm + A(h0) pre-wait.
    // CH0 condition is provably pre-satisfied (full(t-1)==half(t)); CZ real.
    cell_warm(Bl, wg0);
    proA3(Al, h0buf[p], 512, row0);
    wait2(CZ(p ^ 1), 8 * half, CH0(p), 16 * half);
    cell_phase_dma<12, 8>(Al, Bl, gbuf, h0buf[p], 512, zbuf[p ^ 1], 256,
                          wg0, b0r, c0r, h0buf[p ^ 1], row0, j0);
    produce(CH0(p ^ 1));
    // P2: cell1  (K = [h1(t-1) 512 | h0(t) 512]); j<8 may pre-issue A(h1)
    // (guaranteed by own P3(t-1) CH1-wait); j>=8 issues after the wait.
    cell_warm(Bl, wg1);
    if (j < 8) {
      proA3(Al, h1buf[p], 512, row0);
      wait2(CH0(p ^ 1), 16 * full, CH1(p), 16 * half);
    } else {
      wait2(CH0(p ^ 1), 16 * full, CH1(p), 16 * half);
      proA3(Al, h1buf[p], 512, row0);
    }
    cell_phase_dma<16, 8>(Al, Bl, gbuf, h1buf[p], 512, h0buf[p ^ 1], 512,
                          wg1, b1r, c1r, h1buf[p ^ 1], row0, j0);
    produce(CH1(p ^ 1));
    // P3: j<8 -> z(t) = fc(h1(t)); j>=8 -> out(t-1) = lin(z(t-1))
    if (j < 8) {
      wait1(CH1(p ^ 1), 16 * full);
      proj_partials<4>(Atp, gbufp, h1buf[p ^ 1], 512, wpj, row0);
      const int m = threadIdx.x >> 3, nb = (threadIdx.x & 7) * 4;
      const int n0 = j * 32;
      short zz[4];
#pragma unroll
      for (int u = 0; u < 4; ++u) {
        int n = nb + u;
        float v = gbufp[(0 * 64 + m) * 32 + n] + gbufp[(1 * 64 + m) * 32 + n] +
                  gbufp[(2 * 64 + m) * 32 + n] + gbufp[(3 * 64 + m) * 32 + n] +
                  fbr[u];
        zz[u] = f2bf(v);
      }
      ull zv; __builtin_memcpy(&zv, zz, 8);
      *(ull*)&zbuf[p][(size_t)(row0 + m) * 256 + n0 + nb] = zv;
      produce(CZ(p));
    } else if (t > 0) {
      // z(t-1) freshness guaranteed by this step's P1 wait (program order)
      proj_partials<2>(Atp, gbufp, zbuf[p ^ 1], 256, wpj, row0);
      const int m = threadIdx.x >> 3, nb = (threadIdx.x & 7) * 4;
      const int n0 = (j - 8) * 32;
      float4 ov;
      float* po = &ov.x;
#pragma unroll
      for (int u = 0; u < 4; ++u) {
        int n = nb + u;
        po[u] = gbufp[(0 * 64 + m) * 32 + n] + gbufp[(1 * 64 + m) * 32 + n] +
                gbufp[(2 * 64 + m) * 32 + n] + gbufp[(3 * 64 + m) * 32 + n] +
                fbr[u];
      }
      *(float4*)&outp[(size_t)(t - 1) * 262144 + (size_t)(row0 + m) * 256 + n0 + nb] = ov;
    }
  }
  // final out(127) from z(127) in zbuf[1]: z[1] rounds = prep + fc odd t = 65
  if (j >= 8) {
    wait1(CZ(1), 8 * 65);
    proj_partials<2>(Atp, gbufp, zbuf[1], 256, wpj, row0);
    const int m = threadIdx.x >> 3, nb = (threadIdx.x & 7) * 4;
    const int n0 = (j - 8) * 32;
    float4 ov;
    float* po = &ov.x;
#pragma unroll
    for (int u = 0; u < 4; ++u) {
      int n = nb + u;
      po[u] = gbufp[(0 * 64 + m) * 32 + n] + gbufp[(1 * 64 + m) * 32 + n] +
              gbufp[(2 * 64 + m) * 32 + n] + gbufp[(3 * 64 + m) * 32 + n] +
              fbr[u];
    }
    *(float4*)&outp[(size_t)127 * 262144 + (size_t)(row0 + m) * 256 + n0 + nb] = ov;
  }
#undef CZ
#undef CH0
#undef CH1
}

// ---------------------------------------------------------------------------
extern "C" void kernel_launch(void* const* d_in, const int* in_sizes, int n_in,
                              void* d_out, int out_size, void* d_ws, size_t ws_size,
                              hipStream_t stream) {
  const float* z0   = (const float*)d_in[0];
  const float* h0in = (const float*)d_in[1];
  const float* c0in = (const float*)d_in[2];
  const float* Wih0 = (const float*)d_in[3];
  const float* Whh0 = (const float*)d_in[4];
  const float* bih0 = (const float*)d_in[5];
  const float* bhh0 = (const float*)d_in[6];
  const float* Wih1 = (const float*)d_in[7];
  const float* Whh1 = (const float*)d_in[8];
  const float* bih1 = (const float*)d_in[9];
  const float* bhh1 = (const float*)d_in[10];
  const float* fcW  = (const float*)d_in[11];
  const float* fcb  = (const float*)d_in[12];
  const float* linW = (const float*)d_in[13];
  const float* linb = (const float*)d_in[14];
  float* out = (float*)d_out;

  char* ws = (char*)d_ws;
  short* wsw0  = (short*)(ws + 0);         // 3,145,728 B
  short* wsw1  = (short*)(ws + 3145728);   // 4,194,304 B
  short* fcWsw = (short*)(ws + 7340032);   //   262,144 B
  short* linWsw= (short*)(ws + 7602176);   //   131,072 B
  float* bias0 = (float*)(ws + 7733248);   //     8,192 B
  float* bias1 = (float*)(ws + 7741440);   //     8,192 B
  short* zb0   = (short*)(ws + 7749632);   //   524,288 B
  short* zb1   = (short*)(ws + 8273920);   //   524,288 B
  short* h0b0  = (short*)(ws + 8798208);   // 1,048,576 B
  short* h0b1  = (short*)(ws + 9846784);
  short* h1b0  = (short*)(ws + 10895360);
  short* h1b1  = (short*)(ws + 11943936);
  int*   flags = (int*)  (ws + 12992512);  //    33,792 B (total ~13 MB)

  prep_kernel<<<20273, 256, 0, stream>>>(z0, h0in, Wih0, Whh0, bih0, bhh0,
                                         Wih1, Whh1, bih1, bhh1, fcW, linW,
                                         wsw0, wsw1, fcWsw, linWsw, bias0, bias1,
                                         zb1, h0b0, h1b0, flags);

  decoder_persist<<<256, 512, 0, stream>>>(
      wsw0, wsw1, fcWsw, linWsw, bias0, bias1, fcb, linb, c0in,
      h0b0, h0b1, h1b0, h1b1, zb0, zb1, flags, out);
}